// Round 3
// baseline (2842.165 us; speedup 1.0000x reference)
//
#include <hip/hip_runtime.h>

#define T_TOK 8192   // B*S tokens
#define DIM   768
#define NCB   8192   // codebook entries
#define KSEL  8
#define BT    32     // tokens per workgroup
#define BN    128    // codes per tile
#define BD    32     // d-chunk staged in LDS
#define DSTR  140    // dist row stride in floats (16B-aligned)
#define BUFQ  1280   // float4 per staging buffer: xs 256 + cs 1024
#define EXOFF 4608   // exchange region base (floats) = byte 18432 (above dist)
#define MSTR  66     // merge row stride in floats

typedef float v2f __attribute__((ext_vector_type(2)));

// 16B global->LDS DMA. Dest is wave-uniform base + lane*16 (HW rule); all
// per-lane scatter/swizzle lives in the GLOBAL source address.
__device__ __forceinline__ void gload16(const float* g, float4* l) {
  __builtin_amdgcn_global_load_lds(
      (const __attribute__((address_space(1))) void*)g,
      (__attribute__((address_space(3))) void*)l, 16, 0, 0);
}

// ---------------------------------------------------------------------------
// Kernel A: ||row||^2 — bit-exact modern-numpy pairwise_sum (npyv/AVX-512
// W=16) over t[k]=fl32(v*v). [frozen: R5 green — do not change rounding]
// ---------------------------------------------------------------------------
__global__ __launch_bounds__(256) void sq_pairwise_kernel(
    const float* __restrict__ cb, const float* __restrict__ x,
    float* __restrict__ c2out, float* __restrict__ x2out)
{
  #pragma clang fp contract(off)
  __shared__ float part[32][8];
  const int tid = threadIdx.x;
  const int row = blockIdx.x * 32 + (tid >> 3);       // 0..16383
  const int b   = tid & 7;                            // 96-block index
  const float* src = (row < NCB) ? (cb + (size_t)row * DIM)
                                 : (x + (size_t)(row - NCB) * DIM);
  const float* a = src + 96 * b;

  float s[16];
  #pragma unroll
  for (int l = 0; l < 16; ++l) {
    float v, t;
    v = a[l];       t = v * v; float r0 = t;
    v = a[64 + l];  t = v * v; r0 = r0 + t;
    v = a[80 + l];  t = v * v; r0 = r0 + t;
    v = a[16 + l];  t = v * v; float r1 = t;
    v = a[32 + l];  t = v * v; float r2 = t;
    v = a[48 + l];  t = v * v; float r3 = t;
    s[l] = (r0 + r1) + (r2 + r3);
  }
  float t1[8], t2[4];
  #pragma unroll
  for (int i = 0; i < 8; ++i) t1[i] = s[i] + s[i + 8];
  #pragma unroll
  for (int j = 0; j < 4; ++j) t2[j] = t1[j] + t1[j + 4];
  part[tid >> 3][b] = (t2[0] + t2[2]) + (t2[1] + t2[3]);
  __syncthreads();

  if (b == 0) {
    const float* p = part[tid >> 3];
    float res = ((p[0] + p[1]) + (p[2] + p[3])) + ((p[4] + p[5]) + (p[6] + p[7]));
    if (row < NCB) c2out[row] = res;
    else           x2out[row - NCB] = res;
  }
}

// ---------------------------------------------------------------------------
// Kernel B: split-K distance + per-split exact top-8.
// Frozen arithmetic (R5): unfused SSE1 4-lane comb (lane = k&3, ascending k),
// reduce (l0+l2)+(l1+l3), neg = fl(fl(2*xc-x2)-c2), key = -neg (exact).
// SSE-LANE PAIR-SPLIT (R2 structure, R3 fixes xs read stride 1024->512):
// each (tok,code) output is computed by a thread PAIR: half h (= tid>>7,
// whole waves) owns lanes (2h, 2h+1); each lane's full ascending-k chain
// lives in one thread => bit-exact. acc halves to 64 VGPRs ->
// __launch_bounds__(256,4): 4 blocks/CU, 16 waves/CU (2x R1 occupancy).
// LDS layout + DMA staging identical to R1 (full-quad f4, XOR-swizzled cs);
// each half reads its 8B via ds_read_b64 (byte offset +h*8). Tile end: h1
// ships (l2,l3) pairs via LDS (two j-halves, region disjoint from dist),
// h0 does the verbatim frozen combine and writes dist; scan uses 8
// lanes/token (ids still ascend per lane -> tie semantics preserved).
// ---------------------------------------------------------------------------
__global__ __launch_bounds__(256, 4) void dist_topk_kernel(
    const float* __restrict__ x, const float* __restrict__ cb,
    const float* __restrict__ c2g, const float* __restrict__ x2g,
    float* __restrict__ ws, int ncodes)
{
  #pragma clang fp contract(off)
  __shared__ float4 smem4[2 * BUFQ];             // 40960 B (4 blocks/CU exact)
  float* smem = (float*)smem4;
  // buf b: xs = smem4 + b*BUFQ (256 f4, [q][t], 512B per quad-row);
  //   cs = xs + 256 (1024 f4, slot = gx*64 + j*8 + (q^g7), full quads)
  // overlays after d-loop: dist [32][DSTR] @0 (17920B), exch @EXOFF (17408B),
  //   merge md/mi @0 (16896B)

  const int tid  = threadIdx.x;
  const int t0   = blockIdx.x * BT;
  const int nbeg = blockIdx.y * ncodes;

  const int pid = tid & 127;     // pair id (same tok/code tile for both halves)
  const int h   = tid >> 7;      // this thread owns SSE lanes (2h, 2h+1)
  const int gx  = pid & 15;      // 8-code group
  const int gy  = pid >> 4;      // 4-token group: tokens gy*4+i, 0..31
  const int g7  = gx & 7;

  const int tt = tid >> 3;       // scan: token 0..31
  const int cc = tid & 7;        // scan: lane 0..7

  const int wb = tid & ~63;      // wave-uniform DMA dest slot base

  // x DMA: slot = tid -> quad q = tid>>5, token t = tid&31
  const float* xsrc = x + (size_t)(t0 + (tid & 31)) * DIM + (tid >> 5) * 4;

  // cs DMA rounds m: slot s = m*256+tid -> c = s>>3, quad (s&7)^((s>>6)&7)
  int coff[4];
  #pragma unroll
  for (int m = 0; m < 4; ++m) {
    const int s = m * 256 + tid;
    const int c = s >> 3;
    const int q = (s & 7) ^ ((s >> 6) & 7);
    coff[m] = c * DIM + q * 4;
  }

  float x2r[4];
  #pragma unroll
  for (int i = 0; i < 4; ++i) x2r[i] = x2g[t0 + gy * 4 + i];

  float bdist[KSEL]; int bid[KSEL];
  #pragma unroll
  for (int i = 0; i < KSEL; ++i) { bdist[i] = __builtin_inff(); bid[i] = 0x7fffffff; }
  float bmax = __builtin_inff(); int bmaxid = 0x7fffffff; int bslot = 0;

  for (int n0 = nbeg; n0 < nbeg + ncodes; n0 += BN) {
    const float* cbn = cb + (size_t)n0 * DIM;

    v2f acc[4][8];                 // lanes (2h, 2h+1) for 4 tok x 8 codes
    #pragma unroll
    for (int i = 0; i < 4; ++i)
      #pragma unroll
      for (int j = 0; j < 8; ++j) acc[i][j] = (v2f)0.f;

    __syncthreads();               // prev tile's scan/merge smem reads done
    {                              // stage chunk 0 -> buf0
      gload16(xsrc, smem4 + wb);
      #pragma unroll
      for (int m = 0; m < 4; ++m)
        gload16(cbn + coff[m], smem4 + 256 + m * 256 + wb);
    }
    __syncthreads();               // chunk 0 visible (implicit vmcnt(0))

    for (int d0 = 0; d0 < DIM; d0 += BD) {
      const int buf = (d0 >> 5) & 1;
      const int dn = d0 + BD;
      if (dn < DIM) {              // issue next-chunk DMA into other buffer
        float4* nb = smem4 + (buf ^ 1) * BUFQ;
        gload16(xsrc + dn, nb + wb);
        #pragma unroll
        for (int m = 0; m < 4; ++m)
          gload16(cbn + coff[m] + dn, nb + 256 + m * 256 + wb);
      }

      // xs byte: q*512 + (gy*4+i)*16 + h*8; cs byte: 4096 + gx*1024 +
      //   (q^g7)*16 + j*128 + h*8  (all from two base pointers + imm)
      const char* xb  = (const char*)(smem4 + buf * BUFQ) + gy * 64 + h * 8;
      const char* cb8 = (const char*)(smem4 + buf * BUFQ + 256) + gx * 1024 + h * 8;
      #pragma unroll
      for (int q = 0; q < 8; ++q) {
        const v2f xa0 = *(const v2f*)(xb + q * 512);
        const v2f xa1 = *(const v2f*)(xb + q * 512 + 16);
        const v2f xa2 = *(const v2f*)(xb + q * 512 + 32);
        const v2f xa3 = *(const v2f*)(xb + q * 512 + 48);
        const char* cq = cb8 + ((q ^ g7) << 4);
        #pragma unroll
        for (int j = 0; j < 8; ++j) {
          const v2f cv = *(const v2f*)(cq + j * 128);
          v2f p;
          p = xa0 * cv; acc[0][j] = acc[0][j] + p;   // independent fl32 mul/add
          p = xa1 * cv; acc[1][j] = acc[1][j] + p;
          p = xa2 * cv; acc[2][j] = acc[2][j] + p;
          p = xa3 * cv; acc[3][j] = acc[3][j] + p;
        }
      }
      __syncthreads();             // my reads done + next-chunk DMA landed
    }

    // ---- pair exchange (h1 -> h0) + frozen combine + dist write ----
    #pragma unroll
    for (int jb = 0; jb < 8; jb += 4) {
      if (h) {
        float* ex = smem + EXOFF + pid * 34;
        #pragma unroll
        for (int i = 0; i < 4; ++i)
          #pragma unroll
          for (int j2 = 0; j2 < 4; ++j2)
            *(v2f*)(ex + (i * 4 + j2) * 2) = acc[i][jb + j2];
      }
      __syncthreads();
      if (!h) {
        float c2r[4];
        #pragma unroll
        for (int j2 = 0; j2 < 4; ++j2) c2r[j2] = c2g[n0 + gx * 8 + jb + j2];
        const float* ex = smem + EXOFF + pid * 34;
        #pragma unroll
        for (int i = 0; i < 4; ++i) {
          float v[4];
          #pragma unroll
          for (int j2 = 0; j2 < 4; ++j2) {
            const v2f b = *(const v2f*)(ex + (i * 4 + j2) * 2);
            // einsum reduce (l0+l2)+(l1+l3), then literal numpy combine
            const float xc = (acc[i][jb + j2][0] + b[0]) + (acc[i][jb + j2][1] + b[1]);
            const float s  = 2.0f * xc - x2r[i];
            v[j2] = -(s - c2r[j2]);
          }
          *(float4*)&smem[(gy * 4 + i) * DSTR + gx * 8 + jb] =
              make_float4(v[0], v[1], v[2], v[3]);
        }
      }
      __syncthreads();
    }

    // per-lane top-8 (ids ascend in scan; strict < = stable lower-id on ties)
    #pragma unroll
    for (int i2 = 0; i2 < BN / 8; ++i2) {
      const float dval = smem[tt * DSTR + cc + 8 * i2];
      const int   id   = n0 + cc + 8 * i2;
      if (dval < bmax) {
        #pragma unroll
        for (int q = 0; q < KSEL; ++q)
          if (q == bslot) { bdist[q] = dval; bid[q] = id; }
        bmax = bdist[0]; bmaxid = bid[0]; bslot = 0;
        #pragma unroll
        for (int q = 1; q < KSEL; ++q)
          if (bdist[q] > bmax || (bdist[q] == bmax && bid[q] > bmaxid)) {
            bmax = bdist[q]; bmaxid = bid[q]; bslot = q;
          }
      }
    }
    // next tile's staging is gated by the tile-top barrier
  }

  // ---- merge 8 lanes x 8 -> this split's top-8 per token; write to ws ----
  __syncthreads();                     // last scan's dist reads done
  float* md = smem;                    // [32][MSTR]
  int*   mi = (int*)smem + 32 * MSTR;
  #pragma unroll
  for (int j = 0; j < KSEL; ++j) {
    md[tt * MSTR + cc * KSEL + j] = bdist[j];
    mi[tt * MSTR + cc * KSEL + j] = bid[j];
  }
  __syncthreads();
  if (tid < BT) {
    float* mdt = md + tid * MSTR;
    int*   mit = mi + tid * MSTR;
    const size_t base = ((size_t)blockIdx.y * T_TOK + (t0 + tid)) * 16;
    for (int r = 0; r < KSEL; ++r) {
      float best = __builtin_inff(); int bestid = 0x7fffffff; int bs = 0;
      for (int s = 0; s < 64; ++s) {
        const float dv = mdt[s]; const int iv = mit[s];
        if (dv < best || (dv == best && iv < bestid)) { best = dv; bestid = iv; bs = s; }
      }
      mdt[bs] = __builtin_inff();
      ws[base + r] = best;
      ((int*)ws)[base + 8 + r] = bestid;
    }
  }
}

// ---------------------------------------------------------------------------
// Kernel C: exact (val,id)-lex merge of nsplit*8 candidates -> final ids,
// fused with the gather-mean of the 8 selected rows.
// ---------------------------------------------------------------------------
__global__ __launch_bounds__(192) void merge_gather_kernel(
    const float* __restrict__ cb, const float* __restrict__ ws,
    float* __restrict__ out, float* __restrict__ out_ids, int nsplit)
{
  __shared__ float mv[64];
  __shared__ int   mid[64];
  __shared__ int   ssel[KSEL];

  const int t   = blockIdx.x;
  const int tid = threadIdx.x;
  const int ncand = nsplit * KSEL;

  if (tid < ncand) {
    const int s = tid >> 3, r = tid & 7;
    const size_t base = ((size_t)s * T_TOK + t) * 16;
    mv[tid]  = ws[base + r];
    mid[tid] = ((const int*)ws)[base + 8 + r];
  }
  __syncthreads();

  if (tid == 0) {
    for (int r = 0; r < KSEL; ++r) {
      float best = __builtin_inff(); int bestid = 0x7fffffff; int bs = 0;
      for (int s = 0; s < ncand; ++s) {
        const float dv = mv[s]; const int iv = mid[s];
        if (dv < best || (dv == best && iv < bestid)) { best = dv; bestid = iv; bs = s; }
      }
      mv[bs] = __builtin_inff();
      ssel[r] = bestid;
      out_ids[(size_t)t * KSEL + r] = (float)bestid;
    }
  }
  __syncthreads();

  float4 s4 = make_float4(0.f, 0.f, 0.f, 0.f);
  #pragma unroll
  for (int r = 0; r < KSEL; ++r) {
    const float4 v = *(const float4*)(cb + (size_t)ssel[r] * DIM + tid * 4);
    s4.x += v.x; s4.y += v.y; s4.z += v.z; s4.w += v.w;
  }
  s4.x *= 0.125f; s4.y *= 0.125f; s4.z *= 0.125f; s4.w *= 0.125f;
  *(float4*)(out + (size_t)t * DIM + tid * 4) = s4;
}

extern "C" void kernel_launch(void* const* d_in, const int* in_sizes, int n_in,
                              void* d_out, int out_size, void* d_ws, size_t ws_size,
                              hipStream_t stream) {
  (void)in_sizes; (void)n_in; (void)out_size;
  const float* x   = (const float*)d_in[0];
  const float* cbk = (const float*)d_in[1];
  float* out     = (float*)d_out;
  float* c2buf   = out;                   // out[0:8192], overwritten later
  float* x2buf   = out + NCB;             // out[8192:16384], overwritten later
  float* out_ids = out + (size_t)T_TOK * DIM;
  float* ws      = (float*)d_ws;

  int nsplit = 1;
  for (int s = 4; s >= 1; s >>= 1) {
    if ((size_t)s * T_TOK * 16 * 4 <= ws_size) { nsplit = s; break; }
  }
  const int ncodes = NCB / nsplit;

  sq_pairwise_kernel<<<(NCB + T_TOK) / 32, 256, 0, stream>>>(cbk, x, c2buf, x2buf);
  dist_topk_kernel<<<dim3(T_TOK / BT, nsplit), 256, 0, stream>>>(
      x, cbk, c2buf, x2buf, ws, ncodes);
  merge_gather_kernel<<<T_TOK, 192, 0, stream>>>(cbk, ws, out, out_ids, nsplit);
}